// Round 14
// baseline (241.483 us; speedup 1.0000x reference)
//
#include <hip/hip_runtime.h>
#include <math.h>

#define BB 4
#define NN 8192
#define TOTAL (BB*NN)        // 32768 points
#define KNBR 9
#define CH 7
#define NCHUNK 16
#define CHUNK (NN/NCHUNK)    // 512
#define SLOTS 8              // per-chunk kept keys
#define NROWS (NCHUNK*SLOTS) // 128 u32 key rows
#define GSEL 20              // global key-selected candidates for exact re-merge
#define QB 4                 // queries per thread in knn
#define BN_EPS 1e-5f
#define M_ELEMS (TOTAL*KNBR) // 294912
#define NREP 64              // stats replicas, 32-float (128B) stride
#define RSTR 32              // replica stride in floats
#define NBLK 256             // tail kernel blocks
#define NLEAF 16             // barrier tree leaves
#define LSTR 16              // leaf stride in ints

// workspace layout (bytes):
//   pts: knn->sel/feat   pi: knn->sel   nbr: sel->feat   h1(transposed): feat->tail
#define OFF_PTS   0                        // 524288
#define OFF_PI    524288                   // 16777216, ends 17301504
#define OFF_NBR   17301504                 // 9*32768*2 = 589824, ends 17891328
#define OFF_STATS 17891328                 // replicas + barrier tree (zeroed by knn)
#define OFF_H1    17901568                 // 63*32768*4 = 8257536, ends 26159104

// unconditional sorted-shift insert body (desc by d; strict > => earlier arrival
// wins ties; equal-distance candidates arrive in ascending index order => matches
// lax.top_k). Used only in sel's exact merge.
__device__ __forceinline__ void ibody(float (&dl)[10], int (&il)[10], float d, int ii) {
    bool c0 = d > dl[0];
#pragma unroll
    for (int p = 9; p > 0; p--) {
        bool here = d > dl[p];
        bool up   = d > dl[p-1];
        float nd = up ? dl[p-1] : d;
        int   ni = up ? il[p-1] : ii;
        if (here) { dl[p] = nd; il[p] = ni; }
    }
    if (c0) { dl[0] = d; il[0] = ii; }
}

__device__ __forceinline__ void insert10(float (&dl)[10], int (&il)[10], float d, int ii) {
    if (d > dl[9]) ibody(dl, il, d, ii);
}

// ---------------------------------------------------------------- KNN: single-pass packed-key top-8
// (unchanged; 92% of its VALU-issue floor)
__global__ __launch_bounds__(256) void knn_k(const float* __restrict__ x,
                                             float4* __restrict__ pts,
                                             unsigned int* __restrict__ pi,
                                             float* __restrict__ stats) {
    const int b = blockIdx.z, chunk = blockIdx.y;
    const int c0 = chunk * CHUNK;

    if (blockIdx.x == 0 && blockIdx.y == 0 && blockIdx.z == 0) {
        for (int i = threadIdx.x; i < NREP*RSTR + NLEAF*LSTR + 32; i += 256)
            stats[i] = 0.f;                        // stats replicas + barrier tree + flag
    }

    __shared__ float4 tile[CHUNK];                 // (x,y,z,|p|^2) raw
    if (threadIdx.x < CHUNK/4) {
        const float4* __restrict__ x4 = (const float4*)(x + (long)(b*NN + c0)*3);
        int t = threadIdx.x;
        float4 f0 = x4[3*t], f1 = x4[3*t+1], f2 = x4[3*t+2];
        float px[4] = {f0.x, f0.w, f1.z, f2.y};
        float py[4] = {f0.y, f1.x, f1.w, f2.z};
        float pz[4] = {f0.z, f1.y, f2.x, f2.w};
#pragma unroll
        for (int u = 0; u < 4; u++) {
            // bit-exact |p|^2 chain (matches reference xsq rounding)
            float sq = __fadd_rn(__fadd_rn(__fmul_rn(px[u],px[u]), __fmul_rn(py[u],py[u])),
                                 __fmul_rn(pz[u],pz[u]));
            tile[4*t+u] = make_float4(px[u], py[u], pz[u], sq);
        }
    }
    __syncthreads();

    // one designated block per chunk publishes pts
    if (blockIdx.x == 0) {
#pragma unroll
        for (int j = 0; j < CHUNK/256; j++)
            pts[b*NN + c0 + threadIdx.x + j*256] = tile[threadIdx.x + j*256];
    }

    const int q0 = blockIdx.x * (256*QB) + threadIdx.x;
    float qx2[QB], qy2[QB], qz2[QB], nqb[QB];
#pragma unroll
    for (int v = 0; v < QB; v++) {
        long qoff = (long)(b*NN + q0 + v*256) * 3;
        float qx = x[qoff], qy = x[qoff+1], qz = x[qoff+2];
        float qw = qx*qx + qy*qy + qz*qz;   // ranking only; exact chain redone in sel
        qx2[v] = qx + qx; qy2[v] = qy + qy; qz2[v] = qz + qz;
        nqb[v] = -1.0f - qw;
    }

    unsigned int m[QB][SLOTS];
#pragma unroll
    for (int v = 0; v < QB; v++)
#pragma unroll
        for (int s = 0; s < SLOTS; s++) m[v][s] = 0xFFFFFFFFu;

#pragma unroll 4
    for (int j = 0; j < CHUNK; j++) {
        float4 t = tile[j];                        // wave-uniform addr -> LDS broadcast
#pragma unroll
        for (int v = 0; v < QB; v++) {
            float d = fmaf(qx2[v], t.x, fmaf(qy2[v], t.y, fmaf(qz2[v], t.z, nqb[v] - t.w)));
            unsigned int kd = (__float_as_uint(d) & 0xFFFFFE00u) | (unsigned int)j;
#pragma unroll
            for (int p = SLOTS-1; p >= 1; p--)
                asm("v_med3_u32 %0, %1, %2, %3" : "=v"(m[v][p]) : "v"(kd), "v"(m[v][p-1]), "v"(m[v][p]));
            m[v][0] = kd < m[v][0] ? kd : m[v][0];
        }
    }

    // epilogue: rewrite low 13 bits with the global (within-batch) index and store.
#pragma unroll
    for (int v = 0; v < QB; v++) {
        int g = b*NN + q0 + v*256;
#pragma unroll
        for (int s = 0; s < SLOTS; s++) {
            unsigned int mm = m[v][s];
            unsigned int key = (mm & 0xFFFFE000u) | (unsigned int)(c0 + (int)(mm & 511u));
            pi[(long)(chunk*SLOTS + s)*TOTAL + g] = key;
        }
    }
}

// ---------------------------------------------------------------- sel: key-merge + exact top-10 -> 9 u16 indices
// Small register footprint by design (mk[20]+pk[8] stage 1; 4-wide gather batches
// stage 2) so nothing spills to scratch.
__global__ __launch_bounds__(128) void sel_k(const float4* __restrict__ pts,
                                             const unsigned int* __restrict__ pi,
                                             unsigned short* __restrict__ nbr) {
    int g = blockIdx.x * 128 + threadIdx.x;      // 0..32767
    int b = g >> 13, n = g & (NN-1);
    const float4* __restrict__ base = pts + b*NN;
    float4 qp = base[n];
    float qn = -qp.w;

    // stage 1: branchless global top-20 by key (rolled outer loop)
    unsigned int mk[GSEL];
#pragma unroll
    for (int s = 0; s < GSEL; s++) mk[s] = 0xFFFFFFFFu;
#pragma unroll 1
    for (int e8 = 0; e8 < NROWS/8; e8++) {
        unsigned int pk[8];
#pragma unroll
        for (int u = 0; u < 8; u++) pk[u] = pi[(long)(e8*8 + u)*TOTAL + g];
#pragma unroll
        for (int u = 0; u < 8; u++) {
            unsigned int kd = pk[u];
#pragma unroll
            for (int p = GSEL-1; p >= 1; p--)
                asm("v_med3_u32 %0, %1, %2, %3" : "=v"(mk[p]) : "v"(kd), "v"(mk[p-1]), "v"(mk[p]));
            mk[0] = kd < mk[0] ? kd : mk[0];
        }
    }

    // stage 2: exact merge over the 20 selected, in mk (key) order. Equal exact
    // distances share truncated key bits -> ascending-index arrival -> strict >
    // reproduces lax.top_k ties. 4-wide gather batches cap register pressure.
    float dl[10]; int il[10];
#pragma unroll
    for (int j = 0; j < 10; j++) { dl[j] = -INFINITY; il[j] = 0; }
#pragma unroll 1
    for (int hb = 0; hb < 5; hb++) {
        int id[4]; float4 pp[4]; float dd[4];
#pragma unroll
        for (int v = 0; v < 4; v++) { id[v] = (int)(mk[hb*4 + v] & 8191u); pp[v] = base[id[v]]; }
#pragma unroll
        for (int v = 0; v < 4; v++) {
            float dot2 = __fadd_rn(__fadd_rn(__fmul_rn(qp.x, 2.f*pp[v].x),
                                             __fmul_rn(qp.y, 2.f*pp[v].y)),
                                   __fmul_rn(qp.z, 2.f*pp[v].z));
            dd[v] = __fsub_rn(__fadd_rn(dot2, qn), pp[v].w);
        }
#pragma unroll
        for (int v = 0; v < 4; v++) insert10(dl, il, dd[v], id[v]);
    }

    // write 9 neighbor indices (skip slot 0 = self), coalesced u16
#pragma unroll
    for (int t = 0; t < 9; t++)
        nbr[(long)t*TOTAL + g] = (unsigned short)il[t+1];
}

// ---------------------------------------------------------------- feat: geometry + mm1 + h1(transposed) + BN1 stats
// Neighbor vectors live in LDS [t][tid] (conflict-free: bank = tid mod 32 for any
// t); rank->inv permutation in registers. Small reg footprint, coalesced h1 writes.
__global__ __launch_bounds__(128) void feat_k(const float4* __restrict__ pts,
                                              const unsigned short* __restrict__ nbr,
                                              const float* __restrict__ w1,
                                              float* __restrict__ h1, float* __restrict__ stats) {
    __shared__ float sw1[49];
    __shared__ float acc[14];
    __shared__ float vbx[9][128], vby[9][128], vbz[9][128];
    if (threadIdx.x < 49) sw1[threadIdx.x] = w1[threadIdx.x];
    if (threadIdx.x < 14) acc[threadIdx.x] = 0.f;
    __syncthreads();

    int tid = threadIdx.x;
    int g = blockIdx.x * 128 + tid;              // 0..32767
    int b = g >> 13, n = g & (NN-1);
    const float4* __restrict__ base = pts + b*NN;
    float4 qp = base[n];

    // gather 9 neighbors, relative vectors -> LDS, phi -> regs
    float ph[9];
#pragma unroll
    for (int t = 0; t < 9; t++) {
        int idx = (int)nbr[(long)t*TOTAL + g];
        float4 p4 = base[idx];
        float vx = p4.x - qp.x, vy = p4.y - qp.y, vz = p4.z - qp.z;
        vbx[t][tid] = vx; vby[t][tid] = vy; vbz[t][tid] = vz;
        ph[t] = atan2f(vy, vx) / 6.283185307179586f + 0.5f;
    }

    // stable rank sort by phi -> inverse permutation inv[s] = t with rank[t]==s
    int rank[9];
#pragma unroll
    for (int t = 0; t < 9; t++) {
        int r = 0;
#pragma unroll
        for (int u = 0; u < 9; u++) {
            if (u == t) continue;
            bool before = (ph[u] < ph[t]) || (ph[u] == ph[t] && u < t);
            r += before ? 1 : 0;
        }
        rank[t] = r;
    }
    int inv[9];
#pragma unroll
    for (int s = 0; s < 9; s++) {
        int sel = 0;
#pragma unroll
        for (int t = 0; t < 9; t++) sel = (rank[t] == s) ? t : sel;
        inv[s] = sel;
    }

    // sign from first (s=0) normal's x component
    float sgn;
    {
        int t1 = inv[0], t2 = inv[1];
        float ax = vbx[t1][tid], ay = vby[t1][tid], az = vbz[t1][tid];
        float bx = vbx[t2][tid], by = vby[t2][tid], bz = vbz[t2][tid];
        float nx0 = ay*bz - az*by + 1e-5f;
        float ny0 = az*bx - ax*bz + 1e-5f;
        float nz0 = ax*by - ay*bx + 1e-5f;
        float inv2 = 1.0f / sqrtf(nx0*nx0 + ny0*ny0 + nz0*nz0);
        sgn = (nx0*inv2 > 0.0f) ? 1.0f : -1.0f;
    }

    float sum[7], sumsq[7];
#pragma unroll
    for (int o = 0; o < 7; o++) { sum[o] = 0.f; sumsq[o] = 0.f; }

#pragma unroll
    for (int s = 0; s < 9; s++) {
        int t1 = inv[s], t2 = inv[(s+1) % 9];
        float ax = vbx[t1][tid], ay = vby[t1][tid], az = vbz[t1][tid];
        float bx = vbx[t2][tid], by = vby[t2][tid], bz = vbz[t2][tid];
        float cx = 0.5f*(ax+bx), cy = 0.5f*(ay+by), cz = 0.5f*(az+bz);
        float nx0 = ay*bz - az*by + 1e-5f;
        float ny0 = az*bx - ax*bz + 1e-5f;
        float nz0 = ax*by - ay*bx + 1e-5f;
        float inv2 = 1.0f / sqrtf(nx0*nx0 + ny0*ny0 + nz0*nz0);
        float nx = nx0*inv2*sgn, ny = ny0*inv2*sgn, nz = nz0*inv2*sgn;
        float pos = (cx*nx + cy*ny + cz*nz) / 1.7320508075688772f;

        float f[7] = {cx, cy, cz, nx, ny, nz, pos};
#pragma unroll
        for (int o = 0; o < 7; o++) {
            float h = 0.f;
#pragma unroll
            for (int c = 0; c < 7; c++) h += f[c] * sw1[o*7 + c];
            h1[(long)(s*7 + o)*TOTAL + g] = h;   // transposed: coalesced write
            sum[o] += h; sumsq[o] += h*h;
        }
    }

    // wave reduce -> block LDS -> one atomic set per block (64 padded replicas)
#pragma unroll
    for (int o = 0; o < 7; o++) {
        float s  = sum[o];
        float s2 = sumsq[o];
        for (int off = 32; off > 0; off >>= 1) { s += __shfl_down(s, off); s2 += __shfl_down(s2, off); }
        if ((threadIdx.x & 63) == 0) {
            atomicAdd(&acc[o], s);
            atomicAdd(&acc[7 + o], s2);
        }
    }
    __syncthreads();
    if (threadIdx.x < 14)
        atomicAdd(&stats[(blockIdx.x & (NREP-1))*RSTR + threadIdx.x], acc[threadIdx.x]);
}

// ---------------------------------------------------------------- tree grid barrier (round-12 proven)
__device__ __forceinline__ void grid_barrier(int* cnt) {
    __syncthreads();
    if (threadIdx.x == 0) {
        __threadfence();
        int* leaf = &cnt[(blockIdx.x & (NLEAF-1)) * LSTR];
        int old = __hip_atomic_fetch_add(leaf, 1, __ATOMIC_ACQ_REL, __HIP_MEMORY_SCOPE_AGENT);
        if (old == (NBLK/NLEAF) - 1) {
            int rold = __hip_atomic_fetch_add(&cnt[NLEAF*LSTR], 1, __ATOMIC_ACQ_REL, __HIP_MEMORY_SCOPE_AGENT);
            if (rold == NLEAF - 1)
                __hip_atomic_store(&cnt[NLEAF*LSTR + 16], 1, __ATOMIC_RELEASE, __HIP_MEMORY_SCOPE_AGENT);
        }
        while (__hip_atomic_load(&cnt[NLEAF*LSTR + 16], __ATOMIC_ACQUIRE, __HIP_MEMORY_SCOPE_AGENT) == 0)
            __builtin_amdgcn_s_sleep(8);
        __threadfence();
    }
    __syncthreads();
}

// ---------------------------------------------------------------- tail: bn1+mm2 (regs) -> BN2 stats
//                                                                  -> barrier -> bn2+mm3+maxpool -> out
__global__ __launch_bounds__(128) void tail_k(const float* __restrict__ x,
                                              const float* __restrict__ h1,
                                              const float* __restrict__ gamma1, const float* __restrict__ beta1,
                                              const float* __restrict__ w2, const float* __restrict__ bias2,
                                              const float* __restrict__ gamma2, const float* __restrict__ beta2,
                                              const float* __restrict__ w3, const float* __restrict__ bias3,
                                              float* __restrict__ stats, float* __restrict__ out) {
    __shared__ float sw2[49], sw3[49], sb2[7], sb3[7];
    __shared__ float acc[14];
    __shared__ float sco[14];
    if (threadIdx.x < 49) { sw2[threadIdx.x] = w2[threadIdx.x]; sw3[threadIdx.x] = w3[threadIdx.x]; }
    if (threadIdx.x < 7)  { sb2[threadIdx.x] = bias2[threadIdx.x]; sb3[threadIdx.x] = bias3[threadIdx.x]; }
    if (threadIdx.x < 14) acc[threadIdx.x] = 0.f;

    int* cnt = (int*)(stats + NREP*RSTR);
    int g = blockIdx.x * 128 + threadIdx.x;      // 0..32767
    const float invM = 1.0f / (float)M_ELEMS;

    // BN1 scale/shift: 7 threads reduce the 64 replicas into LDS once per block
    if (threadIdx.x < 7) {
        int c = threadIdx.x;
        float sm = 0.f, sq = 0.f;
#pragma unroll
        for (int r = 0; r < NREP; r++) { sm += stats[r*RSTR + c]; sq += stats[r*RSTR + 7 + c]; }
        float m = sm * invM;
        float v = sq * invM - m*m;
        float sc = gamma1[c] / sqrtf(v + BN_EPS);
        sco[c] = sc; sco[7 + c] = beta1[c] - m*sc;
    }
    __syncthreads();
    float s1v[7], b1v[7];
#pragma unroll
    for (int c = 0; c < 7; c++) { s1v[c] = sco[c]; b1v[c] = sco[7 + c]; }

    // phase A: bn1 + relu + w2 + bias2, h2 kept in registers; BN2 stats
    float hv[63];
    float sum[7], sumsq[7];
#pragma unroll
    for (int o = 0; o < 7; o++) { sum[o] = 0.f; sumsq[o] = 0.f; }
#pragma unroll
    for (int t = 0; t < 9; t++) {
        float a[7];
#pragma unroll
        for (int c = 0; c < 7; c++)
            a[c] = fmaxf(h1[(long)(t*7 + c)*TOTAL + g]*s1v[c] + b1v[c], 0.0f);  // coalesced
#pragma unroll
        for (int o = 0; o < 7; o++) {
            float h = 0.f;
#pragma unroll
            for (int c = 0; c < 7; c++) h += a[c] * sw2[o*7 + c];
            h += sb2[o];
            hv[t*7 + o] = h;
            sum[o] += h; sumsq[o] += h*h;
        }
    }
#pragma unroll
    for (int o = 0; o < 7; o++) {
        float s  = sum[o];
        float s2 = sumsq[o];
        for (int off = 32; off > 0; off >>= 1) { s += __shfl_down(s, off); s2 += __shfl_down(s2, off); }
        if ((threadIdx.x & 63) == 0) {
            atomicAdd(&acc[o], s);
            atomicAdd(&acc[7 + o], s2);
        }
    }
    __syncthreads();
    if (threadIdx.x < 14)
        atomicAdd(&stats[(blockIdx.x & (NREP-1))*RSTR + 14 + threadIdx.x], acc[threadIdx.x]);

    // tree grid barrier: BN2 stats complete
    grid_barrier(cnt);

    if (threadIdx.x < 7) {
        int c = threadIdx.x;
        float sm = 0.f, sq = 0.f;
#pragma unroll
        for (int r = 0; r < NREP; r++) {
            sm += __hip_atomic_load(&stats[r*RSTR + 14 + c], __ATOMIC_RELAXED, __HIP_MEMORY_SCOPE_AGENT);
            sq += __hip_atomic_load(&stats[r*RSTR + 21 + c], __ATOMIC_RELAXED, __HIP_MEMORY_SCOPE_AGENT);
        }
        float m = sm * invM;
        float v = sq * invM - m*m;
        float sc = gamma2[c] / sqrtf(v + BN_EPS);
        sco[c] = sc; sco[7 + c] = beta2[c] - m*sc;
    }
    __syncthreads();

    // phase B: bn2 + relu + w3 + bias3 + maxpool -> out
    float pooled[7];
#pragma unroll
    for (int o = 0; o < 7; o++) pooled[o] = -INFINITY;
#pragma unroll
    for (int t = 0; t < 9; t++) {
        float a[7];
#pragma unroll
        for (int c = 0; c < 7; c++) a[c] = fmaxf(hv[t*7 + c]*sco[c] + sco[7 + c], 0.0f);
#pragma unroll
        for (int o = 0; o < 7; o++) {
            float h = 0.f;
#pragma unroll
            for (int c = 0; c < 7; c++) h += a[c] * sw3[o*7 + c];
            h += sb3[o];
            pooled[o] = fmaxf(pooled[o], h);
        }
    }
    out[g*10 + 0] = x[g*3 + 0];
    out[g*10 + 1] = x[g*3 + 1];
    out[g*10 + 2] = x[g*3 + 2];
#pragma unroll
    for (int o = 0; o < 7; o++) out[g*10 + 3 + o] = pooled[o];
}

extern "C" void kernel_launch(void* const* d_in, const int* in_sizes, int n_in,
                              void* d_out, int out_size, void* d_ws, size_t ws_size,
                              hipStream_t stream) {
    const float* x      = (const float*)d_in[0];
    const float* w1     = (const float*)d_in[1];
    const float* gamma1 = (const float*)d_in[2];
    const float* beta1  = (const float*)d_in[3];
    const float* w2     = (const float*)d_in[4];
    const float* bias2  = (const float*)d_in[5];
    const float* gamma2 = (const float*)d_in[6];
    const float* beta2  = (const float*)d_in[7];
    const float* w3     = (const float*)d_in[8];
    const float* bias3  = (const float*)d_in[9];
    float* out = (float*)d_out;

    char* ws = (char*)d_ws;
    float4*         pts  = (float4*)(ws + OFF_PTS);
    unsigned int*   pi   = (unsigned int*)(ws + OFF_PI);
    unsigned short* nbr  = (unsigned short*)(ws + OFF_NBR);
    float*          stats= (float*)(ws + OFF_STATS);
    float*          h1   = (float*)(ws + OFF_H1);

    knn_k <<<dim3(NN/(256*QB), NCHUNK, BB), 256, 0, stream>>>(x, pts, pi, stats);
    sel_k <<<TOTAL/128, 128, 0, stream>>>(pts, pi, nbr);
    feat_k<<<TOTAL/128, 128, 0, stream>>>(pts, nbr, w1, h1, stats);
    tail_k<<<NBLK, 128, 0, stream>>>(x, h1, gamma1, beta1, w2, bias2,
                                     gamma2, beta2, w3, bias3, stats, out);
}

// Round 15
// 222.803 us; speedup vs baseline: 1.0838x; 1.0838x over previous
//
#include <hip/hip_runtime.h>
#include <math.h>

#define BB 4
#define NN 8192
#define TOTAL (BB*NN)        // 32768 points
#define KNBR 9
#define CH 7
#define NCHUNK 16
#define CHUNK (NN/NCHUNK)    // 512
#define SLOTS 8              // per-chunk kept keys. Union-of-top-8 misses global top-10
                             // only if one chunk holds >=9 of it (P~2e-9/query, 8e-5/run).
#define NROWS (NCHUNK*SLOTS) // 128 u32 key rows
#define GSEL 20              // global key-selected candidates for exact re-merge
#define QB 4                 // queries per thread in knn (amortizes LDS broadcast read)
#define BN_EPS 1e-5f
#define M_ELEMS (TOTAL*KNBR) // 294912
#define NREP 16              // stats replicas (atomic contention / 16)
#define NBLK 256             // tail kernel blocks (512 waves, trivially co-resident)

// workspace layout (bytes); lifetimes:
//   pts: knn->geom   pi: knn->geom   h1: geom->tail   stats+cnt: knn(zero)->tail
#define OFF_PTS   0                        // 524288
#define OFF_PI    524288                   // 32768*128*4 = 16777216, ends 17301504
#define OFF_STATS 17301504                 // NREP*28 floats + counter (zeroed by knn), pad 2048
#define OFF_H1    17303552                 // 8257536, ends 25561088

// unconditional sorted-shift insert body (desc by d; strict > => earlier arrival
// wins ties; equal-distance candidates arrive in ascending index order => matches
// lax.top_k). Used only in geom's exact merge.
__device__ __forceinline__ void ibody(float (&dl)[10], int (&il)[10], float d, int ii) {
    bool c0 = d > dl[0];
#pragma unroll
    for (int p = 9; p > 0; p--) {
        bool here = d > dl[p];
        bool up   = d > dl[p-1];
        float nd = up ? dl[p-1] : d;
        int   ni = up ? il[p-1] : ii;
        if (here) { dl[p] = nd; il[p] = ni; }
    }
    if (c0) { dl[0] = d; il[0] = ii; }
}

__device__ __forceinline__ void insert10(float (&dl)[10], int (&il)[10], float d, int ii) {
    if (d > dl[9]) ibody(dl, il, d, ii);
}

// ---------------------------------------------------------------- KNN: single-pass packed-key top-8
// Ranking key: d'' = 2*q.c - |c|^2 - (|q|^2 + 1)  (strictly < -1, sign bit set; top
// candidates sit near -1 => truncation quantum tiny; boundary ties re-resolved
// exactly in geom's merge). Negative floats: unsigned bit order is REVERSED float
// order -> the 8 SMALLEST u32 keys are the 8 LARGEST d''. Low 9 bits replaced by
// in-chunk index j (CHUNK=512) during the scan; the epilogue rewrites low 13 bits
// with the GLOBAL index (13-bit truncation) so geom can merge keys across chunks
// without recomputing distances. QB=4 queries/thread amortizes the LDS read.
__global__ __launch_bounds__(256) void knn_k(const float* __restrict__ x,
                                             float4* __restrict__ pts,
                                             unsigned int* __restrict__ pi,
                                             float* __restrict__ stats) {
    const int b = blockIdx.z, chunk = blockIdx.y;
    const int c0 = chunk * CHUNK;

    if (blockIdx.x == 0 && blockIdx.y == 0 && blockIdx.z == 0) {
        for (int i = threadIdx.x; i < NREP*28 + 8; i += 256) stats[i] = 0.f;  // stats + barrier counter
    }

    __shared__ float4 tile[CHUNK];                 // (x,y,z,|p|^2) raw
    if (threadIdx.x < CHUNK/4) {
        // stage chunk points from x: thread t unpacks points 4t..4t+3 from 3 float4 loads
        const float4* __restrict__ x4 = (const float4*)(x + (long)(b*NN + c0)*3);
        int t = threadIdx.x;
        float4 f0 = x4[3*t], f1 = x4[3*t+1], f2 = x4[3*t+2];
        float px[4] = {f0.x, f0.w, f1.z, f2.y};
        float py[4] = {f0.y, f1.x, f1.w, f2.z};
        float pz[4] = {f0.z, f1.y, f2.x, f2.w};
#pragma unroll
        for (int u = 0; u < 4; u++) {
            // bit-exact |p|^2 chain (matches reference xsq rounding)
            float sq = __fadd_rn(__fadd_rn(__fmul_rn(px[u],px[u]), __fmul_rn(py[u],py[u])),
                                 __fmul_rn(pz[u],pz[u]));
            tile[4*t+u] = make_float4(px[u], py[u], pz[u], sq);
        }
    }
    __syncthreads();

    // one designated block per chunk publishes pts for geom's gathers
    if (blockIdx.x == 0) {
#pragma unroll
        for (int j = 0; j < CHUNK/256; j++)
            pts[b*NN + c0 + threadIdx.x + j*256] = tile[threadIdx.x + j*256];
    }

    // four query points per thread, 256 apart (keeps loads/stores coalesced)
    const int q0 = blockIdx.x * (256*QB) + threadIdx.x;
    float qx2[QB], qy2[QB], qz2[QB], nqb[QB];
#pragma unroll
    for (int v = 0; v < QB; v++) {
        long qoff = (long)(b*NN + q0 + v*256) * 3;
        float qx = x[qoff], qy = x[qoff+1], qz = x[qoff+2];
        // ranking only needs monotonicity; exact chain redone in geom merge
        float qw = qx*qx + qy*qy + qz*qz;
        qx2[v] = qx + qx; qy2[v] = qy + qy; qz2[v] = qz + qz;
        nqb[v] = -1.0f - qw;
    }

    unsigned int m[QB][SLOTS];
#pragma unroll
    for (int v = 0; v < QB; v++)
#pragma unroll
        for (int s = 0; s < SLOTS; s++) m[v][s] = 0xFFFFFFFFu;

#pragma unroll 4
    for (int j = 0; j < CHUNK; j++) {
        float4 t = tile[j];                        // wave-uniform addr -> LDS broadcast
#pragma unroll
        for (int v = 0; v < QB; v++) {
            float d = fmaf(qx2[v], t.x, fmaf(qy2[v], t.y, fmaf(qz2[v], t.z, nqb[v] - t.w)));
            unsigned int kd = (__float_as_uint(d) & 0xFFFFFE00u) | (unsigned int)j;
            // branchless min-8 shift register (ascending); all reads are old values
#pragma unroll
            for (int p = SLOTS-1; p >= 1; p--)
                asm("v_med3_u32 %0, %1, %2, %3" : "=v"(m[v][p]) : "v"(kd), "v"(m[v][p-1]), "v"(m[v][p]));
            m[v][0] = kd < m[v][0] ? kd : m[v][0];
        }
    }

    // epilogue: rewrite low 13 bits with the global (within-batch) index and store.
    // Keys stay u32-comparable across chunks (13-bit truncated distance bits);
    // within a truncation bucket, lower global index -> smaller key (top_k tie rule).
#pragma unroll
    for (int v = 0; v < QB; v++) {
        int g = b*NN + q0 + v*256;
#pragma unroll
        for (int s = 0; s < SLOTS; s++) {
            unsigned int mm = m[v][s];
            unsigned int key = (mm & 0xFFFFE000u) | (unsigned int)(c0 + (int)(mm & 511u));
            pi[(long)(chunk*SLOTS + s)*TOTAL + g] = key;
        }
    }
}

// ---------------------------------------------------------------- key-merge + geometry + feat + h1 + BN1 stats
// Stage-1 loop is ROLLED with a register double-buffer: batch e8+1's 8 loads issue
// before batch e8's med3 chain consumes, overlapping HBM latency with VALU work
// across the 16-iteration serial chain.
__global__ __launch_bounds__(128) void geom_k(const float4* __restrict__ pts,
                                              const unsigned int* __restrict__ pi,
                                              const float* __restrict__ w1,
                                              float* __restrict__ h1, float* __restrict__ stats) {
    __shared__ float sw1[49];
    __shared__ float acc[14];
    if (threadIdx.x < 49) sw1[threadIdx.x] = w1[threadIdx.x];
    if (threadIdx.x < 14) acc[threadIdx.x] = 0.f;
    __syncthreads();

    int g = blockIdx.x * 128 + threadIdx.x;      // 0..32767
    int b = g >> 13, n = g & (NN-1);
    const float4* __restrict__ base = pts + b*NN;
    float4 qp = base[n];
    float qn = -qp.w;

    // ---- stage 1: branchless global top-20 by key (the key IS the index carrier).
    // Rolled outer loop; pkA/pkB double-buffer hides each batch's load latency
    // under the previous batch's 168 med3 ops.
    unsigned int mk[GSEL];
#pragma unroll
    for (int s = 0; s < GSEL; s++) mk[s] = 0xFFFFFFFFu;
    unsigned int pkA[8], pkB[8];
#pragma unroll
    for (int u = 0; u < 8; u++) pkA[u] = pi[(long)u*TOTAL + g];
#pragma unroll 1
    for (int e8 = 0; e8 < NROWS/8; e8++) {
        if (e8 + 1 < NROWS/8) {
#pragma unroll
            for (int u = 0; u < 8; u++) pkB[u] = pi[(long)((e8+1)*8 + u)*TOTAL + g];
        }
#pragma unroll
        for (int u = 0; u < 8; u++) {
            unsigned int kd = pkA[u];
#pragma unroll
            for (int p = GSEL-1; p >= 1; p--)
                asm("v_med3_u32 %0, %1, %2, %3" : "=v"(mk[p]) : "v"(kd), "v"(mk[p-1]), "v"(mk[p]));
            mk[0] = kd < mk[0] ? kd : mk[0];
        }
#pragma unroll
        for (int u = 0; u < 8; u++) pkA[u] = pkB[u];
    }

    // ---- stage 2: exact merge over the 20 selected, in mk (key) order.
    // Equal exact distances have identical truncated key bits, so mk order places
    // equal-distance candidates in ascending-index order; insert10's strict-> then
    // reproduces lax.top_k tie rules. Two batches of 10 gathers.
    float dl[10]; int il[10];
#pragma unroll
    for (int j = 0; j < 10; j++) { dl[j] = -INFINITY; il[j] = 0; }
#pragma unroll
    for (int hb = 0; hb < 2; hb++) {
        int id[10];
        float4 pp[10];
#pragma unroll
        for (int v = 0; v < 10; v++) { id[v] = (int)(mk[hb*10 + v] & 8191u); pp[v] = base[id[v]]; }
        float dd[10];
#pragma unroll
        for (int v = 0; v < 10; v++) {
            float dot2 = __fadd_rn(__fadd_rn(__fmul_rn(qp.x, 2.f*pp[v].x),
                                             __fmul_rn(qp.y, 2.f*pp[v].y)),
                                   __fmul_rn(qp.z, 2.f*pp[v].z));
            dd[v] = __fsub_rn(__fadd_rn(dot2, qn), pp[v].w);
        }
#pragma unroll
        for (int v = 0; v < 10; v++) insert10(dl, il, dd[v], id[v]);
    }

    // gather 9 neighbors (skip slot 0 = self), relative vectors + phi
    float vx[9], vy[9], vz[9], ph[9];
#pragma unroll
    for (int t = 0; t < 9; t++) {
        float4 p4 = base[il[t+1]];
        vx[t] = p4.x - qp.x; vy[t] = p4.y - qp.y; vz[t] = p4.z - qp.z;
        ph[t] = atan2f(vy[t], vx[t]) / 6.283185307179586f + 0.5f;
    }

    // stable rank sort by phi (static indexing, branchless scatter)
    int rank[9];
#pragma unroll
    for (int t = 0; t < 9; t++) {
        int r = 0;
#pragma unroll
        for (int u = 0; u < 9; u++) {
            if (u == t) continue;
            bool before = (ph[u] < ph[t]) || (ph[u] == ph[t] && u < t);
            r += before ? 1 : 0;
        }
        rank[t] = r;
    }
    float sx[9], sy[9], sz[9];
#pragma unroll
    for (int s = 0; s < 9; s++) {
        float a = 0.f, bb = 0.f, c = 0.f;
#pragma unroll
        for (int t = 0; t < 9; t++) {
            bool m = (rank[t] == s);
            a = m ? vx[t] : a; bb = m ? vy[t] : bb; c = m ? vz[t] : c;
        }
        sx[s] = a; sy[s] = bb; sz[s] = c;
    }

    // sign from first (k=0) normal's x component
    float sgn;
    {
        float ax = sx[0], ay = sy[0], az = sz[0];
        float bx = sx[1], by = sy[1], bz = sz[1];
        float nx0 = ay*bz - az*by + 1e-5f;
        float ny0 = az*bx - ax*bz + 1e-5f;
        float nz0 = ax*by - ay*bx + 1e-5f;
        float inv = 1.0f / sqrtf(nx0*nx0 + ny0*ny0 + nz0*nz0);
        sgn = (nx0*inv > 0.0f) ? 1.0f : -1.0f;
    }

    float sum[7], sumsq[7];
#pragma unroll
    for (int o = 0; o < 7; o++) { sum[o] = 0.f; sumsq[o] = 0.f; }

#pragma unroll
    for (int t = 0; t < 9; t++) {
        const int t2 = (t + 1) % 9;
        float ax = sx[t],  ay = sy[t],  az = sz[t];
        float bx = sx[t2], by = sy[t2], bz = sz[t2];
        float cx = 0.5f*(ax+bx), cy = 0.5f*(ay+by), cz = 0.5f*(az+bz);
        float nx0 = ay*bz - az*by + 1e-5f;
        float ny0 = az*bx - ax*bz + 1e-5f;
        float nz0 = ax*by - ay*bx + 1e-5f;
        float inv = 1.0f / sqrtf(nx0*nx0 + ny0*ny0 + nz0*nz0);
        float nx = nx0*inv*sgn, ny = ny0*inv*sgn, nz = nz0*inv*sgn;
        float pos = (cx*nx + cy*ny + cz*nz) / 1.7320508075688772f;

        float f[7] = {cx, cy, cz, nx, ny, nz, pos};
        float* outp = h1 + ((long)g*9 + t) * 7;
#pragma unroll
        for (int o = 0; o < 7; o++) {
            float h = 0.f;
#pragma unroll
            for (int c = 0; c < 7; c++) h += f[c] * sw1[o*7 + c];
            outp[o] = h;
            sum[o] += h; sumsq[o] += h*h;
        }
    }

    // wave reduce -> block LDS -> one atomic set per block (16-replica stats)
#pragma unroll
    for (int o = 0; o < 7; o++) {
        float s  = sum[o];
        float s2 = sumsq[o];
        for (int off = 32; off > 0; off >>= 1) { s += __shfl_down(s, off); s2 += __shfl_down(s2, off); }
        if ((threadIdx.x & 63) == 0) {
            atomicAdd(&acc[o], s);
            atomicAdd(&acc[7 + o], s2);
        }
    }
    __syncthreads();
    if (threadIdx.x < 14)
        atomicAdd(&stats[(blockIdx.x & (NREP-1))*28 + threadIdx.x], acc[threadIdx.x]);
}

// ---------------------------------------------------------------- software grid barrier
// 256 blocks x 128 threads = 512 waves: trivially co-resident at any VGPR count.
// Device-scope release add + agent-scope acquire spin; cross-XCD safe (G16).
__device__ __forceinline__ void grid_barrier(int* cnt) {
    __syncthreads();
    if (threadIdx.x == 0) {
        __threadfence();
        __hip_atomic_fetch_add(cnt, 1, __ATOMIC_RELEASE, __HIP_MEMORY_SCOPE_AGENT);
        while (__hip_atomic_load(cnt, __ATOMIC_ACQUIRE, __HIP_MEMORY_SCOPE_AGENT) < NBLK)
            __builtin_amdgcn_s_sleep(8);
    }
    __syncthreads();
}

// ---------------------------------------------------------------- tail: bn1+mm2 (regs) -> BN2 stats
//                                                                  -> barrier -> bn2+mm3+maxpool -> out
// h2 lives in 63 registers; math chains identical to the split mm2/final kernels.
__global__ __launch_bounds__(128) void tail_k(const float* __restrict__ x,
                                              const float* __restrict__ h1,
                                              const float* __restrict__ gamma1, const float* __restrict__ beta1,
                                              const float* __restrict__ w2, const float* __restrict__ bias2,
                                              const float* __restrict__ gamma2, const float* __restrict__ beta2,
                                              const float* __restrict__ w3, const float* __restrict__ bias3,
                                              float* __restrict__ stats, float* __restrict__ out) {
    __shared__ float sw2[49], sw3[49], sb2[7], sb3[7];
    __shared__ float acc[14];
    __shared__ float sco[14];
    if (threadIdx.x < 49) { sw2[threadIdx.x] = w2[threadIdx.x]; sw3[threadIdx.x] = w3[threadIdx.x]; }
    if (threadIdx.x < 7)  { sb2[threadIdx.x] = bias2[threadIdx.x]; sb3[threadIdx.x] = bias3[threadIdx.x]; }
    if (threadIdx.x < 14) acc[threadIdx.x] = 0.f;
    __syncthreads();

    int* cnt = (int*)(stats + NREP*28);
    int g = blockIdx.x * 128 + threadIdx.x;      // 0..32767
    const float invM = 1.0f / (float)M_ELEMS;

    // BN1 scale/shift (replica sum; same arithmetic as the split mm2_k)
    float s1v[7], b1v[7];
#pragma unroll
    for (int c = 0; c < 7; c++) {
        float sm = 0.f, sq = 0.f;
#pragma unroll
        for (int r = 0; r < NREP; r++) { sm += stats[r*28 + c]; sq += stats[r*28 + 7 + c]; }
        float m = sm * invM;
        float v = sq * invM - m*m;
        float sc = gamma1[c] / sqrtf(v + BN_EPS);
        s1v[c] = sc; b1v[c] = beta1[c] - m*sc;
    }

    // phase A: bn1 + relu + w2 + bias2, h2 kept in registers; BN2 stats
    float hv[63];
    float sum[7], sumsq[7];
#pragma unroll
    for (int o = 0; o < 7; o++) { sum[o] = 0.f; sumsq[o] = 0.f; }
    const float* hh = h1 + (long)g * 63;
#pragma unroll
    for (int t = 0; t < 9; t++) {
        float a[7];
#pragma unroll
        for (int c = 0; c < 7; c++) a[c] = fmaxf(hh[t*7 + c]*s1v[c] + b1v[c], 0.0f);
#pragma unroll
        for (int o = 0; o < 7; o++) {
            float h = 0.f;
#pragma unroll
            for (int c = 0; c < 7; c++) h += a[c] * sw2[o*7 + c];
            h += sb2[o];
            hv[t*7 + o] = h;
            sum[o] += h; sumsq[o] += h*h;
        }
    }
#pragma unroll
    for (int o = 0; o < 7; o++) {
        float s  = sum[o];
        float s2 = sumsq[o];
        for (int off = 32; off > 0; off >>= 1) { s += __shfl_down(s, off); s2 += __shfl_down(s2, off); }
        if ((threadIdx.x & 63) == 0) {
            atomicAdd(&acc[o], s);
            atomicAdd(&acc[7 + o], s2);
        }
    }
    __syncthreads();
    if (threadIdx.x < 14)
        atomicAdd(&stats[(blockIdx.x & (NREP-1))*28 + 14 + threadIdx.x], acc[threadIdx.x]);

    // grid barrier: BN2 stats complete
    grid_barrier(cnt);

    if (threadIdx.x < 7) {
        int c = threadIdx.x;
        float sm = 0.f, sq = 0.f;
#pragma unroll
        for (int r = 0; r < NREP; r++) {
            sm += __hip_atomic_load(&stats[r*28 + 14 + c], __ATOMIC_RELAXED, __HIP_MEMORY_SCOPE_AGENT);
            sq += __hip_atomic_load(&stats[r*28 + 21 + c], __ATOMIC_RELAXED, __HIP_MEMORY_SCOPE_AGENT);
        }
        float m = sm * invM;
        float v = sq * invM - m*m;
        float sc = gamma2[c] / sqrtf(v + BN_EPS);
        sco[c] = sc; sco[7 + c] = beta2[c] - m*sc;
    }
    __syncthreads();

    // phase B: bn2 + relu + w3 + bias3 + maxpool -> out
    float pooled[7];
#pragma unroll
    for (int o = 0; o < 7; o++) pooled[o] = -INFINITY;
#pragma unroll
    for (int t = 0; t < 9; t++) {
        float a[7];
#pragma unroll
        for (int c = 0; c < 7; c++) a[c] = fmaxf(hv[t*7 + c]*sco[c] + sco[7 + c], 0.0f);
#pragma unroll
        for (int o = 0; o < 7; o++) {
            float h = 0.f;
#pragma unroll
            for (int c = 0; c < 7; c++) h += a[c] * sw3[o*7 + c];
            h += sb3[o];
            pooled[o] = fmaxf(pooled[o], h);
        }
    }
    out[g*10 + 0] = x[g*3 + 0];
    out[g*10 + 1] = x[g*3 + 1];
    out[g*10 + 2] = x[g*3 + 2];
#pragma unroll
    for (int o = 0; o < 7; o++) out[g*10 + 3 + o] = pooled[o];
}

extern "C" void kernel_launch(void* const* d_in, const int* in_sizes, int n_in,
                              void* d_out, int out_size, void* d_ws, size_t ws_size,
                              hipStream_t stream) {
    const float* x      = (const float*)d_in[0];
    const float* w1     = (const float*)d_in[1];
    const float* gamma1 = (const float*)d_in[2];
    const float* beta1  = (const float*)d_in[3];
    const float* w2     = (const float*)d_in[4];
    const float* bias2  = (const float*)d_in[5];
    const float* gamma2 = (const float*)d_in[6];
    const float* beta2  = (const float*)d_in[7];
    const float* w3     = (const float*)d_in[8];
    const float* bias3  = (const float*)d_in[9];
    float* out = (float*)d_out;

    char* ws = (char*)d_ws;
    float4*       pts  = (float4*)(ws + OFF_PTS);
    unsigned int* pi   = (unsigned int*)(ws + OFF_PI);
    float*        stats= (float*)(ws + OFF_STATS);
    float*        h1   = (float*)(ws + OFF_H1);

    knn_k <<<dim3(NN/(256*QB), NCHUNK, BB), 256, 0, stream>>>(x, pts, pi, stats);
    geom_k<<<TOTAL/128, 128, 0, stream>>>(pts, pi, w1, h1, stats);
    tail_k<<<NBLK, 128, 0, stream>>>(x, h1, gamma1, beta1, w2, bias2,
                                     gamma2, beta2, w3, bias3, stats, out);
}